// Round 2
// baseline (602.336 us; speedup 1.0000x reference)
//
#include <hip/hip_runtime.h>
#include <math.h>

#define NROWS 16384
#define DIN   2048
#define H1D   256
#define H2D   128
#define NE    64
#define BM    32
#define BK    32
#define NTHREADS 256

// LDS layout (bytes), all f32 storage (inputs are exact f32; intermediates
// stored f32 cost ~1e-8 at logit level -- negligible):
//  [0,     4608)  : sX[32][36]    (stage 1)  } region A -- reused as sH2[32][132]
//  [4608, 37376)  : sW[32][256]   (stage 1)  }
//  [37376,70144)  : sH1[32][256]  (stage 1 -> 2)
//  [70144,70656)  : sTop[32][4]
#define SMEM_BYTES (4608 + 32768 + 32768 + 512)

#define SQRT1_2 0.70710678118654752440084436210485

__global__ __launch_bounds__(NTHREADS, 2)
void fused_gate_kernel(const float* __restrict__ x,
                       const float* __restrict__ w1, const float* __restrict__ b1,
                       const float* __restrict__ g1, const float* __restrict__ be1,
                       const float* __restrict__ w2, const float* __restrict__ b2,
                       const float* __restrict__ g2, const float* __restrict__ be2,
                       const float* __restrict__ w3, const float* __restrict__ b3,
                       const float* __restrict__ temperature,
                       float* __restrict__ out_gates,
                       float* __restrict__ out_idx,
                       float* __restrict__ out_logits)
{
    __shared__ __align__(16) char smem[SMEM_BYTES];
    float (*sX)[BM + 4]   = (float (*)[BM + 4])(smem);
    float (*sW)[H1D]      = (float (*)[H1D])(smem + 4608);
    float (*sH2)[H2D + 4] = (float (*)[H2D + 4])(smem);           // reuses region A (+ dead sW space)
    float (*sH1)[H1D]     = (float (*)[H1D])(smem + 4608 + 32768);
    float (*sTop)[4]      = (float (*)[4])(smem + 4608 + 32768 + 32768);

    const int tid = threadIdx.x;
    const int tx  = tid & 31;   // 0..31
    const int ty  = tid >> 5;   // 0..7
    const int r0  = blockIdx.x * BM;

    // ---------------- Stage 1: C1 = x @ w1 (tile BM x 256), f64 accumulate ----------------
    double acc[4][8];
    #pragma unroll
    for (int i = 0; i < 4; ++i)
        #pragma unroll
        for (int j = 0; j < 8; ++j) acc[i][j] = 0.0;

    const int lrow = tid >> 3;  // 0..31 (x tile row)
    const int lf4  = tid & 7;   // 0..7  (x tile float4 col)
    const float* xrow = x + (size_t)(r0 + lrow) * DIN + lf4 * 4;

    for (int kt = 0; kt < DIN; kt += BK) {
        float4 xv = *(const float4*)(xrow + kt);
        float4 wv[8];
        const float4* wsrc = (const float4*)(w1 + (size_t)kt * H1D);
        #pragma unroll
        for (int i = 0; i < 8; ++i) wv[i] = wsrc[tid + i * NTHREADS];
        __syncthreads();
        sX[lf4 * 4 + 0][lrow] = xv.x;
        sX[lf4 * 4 + 1][lrow] = xv.y;
        sX[lf4 * 4 + 2][lrow] = xv.z;
        sX[lf4 * 4 + 3][lrow] = xv.w;
        {
            float4* wdst = (float4*)(&sW[0][0]);
            #pragma unroll
            for (int i = 0; i < 8; ++i) wdst[tid + i * NTHREADS] = wv[i];
        }
        __syncthreads();
        #pragma unroll
        for (int kk = 0; kk < BK; ++kk) {
            float4 av = *(const float4*)(&sX[kk][ty * 4]);
            double a64[4] = {(double)av.x, (double)av.y, (double)av.z, (double)av.w};
            double b64[8];
            #pragma unroll
            for (int j = 0; j < 8; ++j) b64[j] = (double)sW[kk][tx + 32 * j];
            #pragma unroll
            for (int i = 0; i < 4; ++i)
                #pragma unroll
                for (int j = 0; j < 8; ++j)
                    acc[i][j] = fma(a64[i], b64[j], acc[i][j]);
        }
    }

    // bias + LayerNorm(H1) + exact GELU, all f64 math; store h1 tile f32
    #pragma unroll
    for (int i = 0; i < 4; ++i) {
        double s1 = 0.0, s2 = 0.0;
        double v[8];
        #pragma unroll
        for (int j = 0; j < 8; ++j) {
            double t = acc[i][j] + (double)b1[tx + 32 * j];
            v[j] = t;
            s1 += t; s2 += t * t;
        }
        for (int m = 1; m < 32; m <<= 1) {
            s1 += __shfl_xor(s1, m, 64);
            s2 += __shfl_xor(s2, m, 64);
        }
        double mu  = s1 * (1.0 / H1D);
        double var = s2 * (1.0 / H1D) - mu * mu;
        double rs  = 1.0 / sqrt(var + 1e-5);
        #pragma unroll
        for (int j = 0; j < 8; ++j) {
            int c = tx + 32 * j;
            double vn = (v[j] - mu) * rs * (double)g1[c] + (double)be1[c];
            double ge = 0.5 * vn * (1.0 + erf(vn * SQRT1_2));
            sH1[ty * 4 + i][c] = (float)ge;
        }
    }
    __syncthreads();

    // ---------------- Stage 2: C2 = h1 @ w2 (BM x 128), f64 accumulate ----------------
    double acc2[4][4];
    #pragma unroll
    for (int i = 0; i < 4; ++i)
        #pragma unroll
        for (int j = 0; j < 4; ++j) acc2[i][j] = 0.0;
    {
        const float* w2p = w2 + tx * 4;
        for (int k = 0; k < H1D; ++k) {
            float4 wv4 = *(const float4*)(w2p + (size_t)k * H2D);
            double wr[4] = {(double)wv4.x, (double)wv4.y, (double)wv4.z, (double)wv4.w};
            double ar[4];
            #pragma unroll
            for (int i = 0; i < 4; ++i) ar[i] = (double)sH1[ty * 4 + i][k];
            #pragma unroll
            for (int i = 0; i < 4; ++i)
                #pragma unroll
                for (int j = 0; j < 4; ++j)
                    acc2[i][j] = fma(ar[i], wr[j], acc2[i][j]);
        }
    }

    // bias + LayerNorm(H2) + GELU (f64) -> sH2 (f32; overwrites dead stage-1 regions)
    #pragma unroll
    for (int i = 0; i < 4; ++i) {
        double s1 = 0.0, s2 = 0.0;
        double vv[4];
        #pragma unroll
        for (int j = 0; j < 4; ++j) {
            double t = acc2[i][j] + (double)b2[tx * 4 + j];
            vv[j] = t;
            s1 += t; s2 += t * t;
        }
        for (int m = 1; m < 32; m <<= 1) {
            s1 += __shfl_xor(s1, m, 64);
            s2 += __shfl_xor(s2, m, 64);
        }
        double mu  = s1 * (1.0 / H2D);
        double var = s2 * (1.0 / H2D) - mu * mu;
        double rs  = 1.0 / sqrt(var + 1e-5);
        #pragma unroll
        for (int j = 0; j < 4; ++j) {
            int c = tx * 4 + j;
            double vn = (vv[j] - mu) * rs * (double)g2[c] + (double)be2[c];
            double ge = 0.5 * vn * (1.0 + erf(vn * SQRT1_2));
            sH2[ty * 4 + i][c] = (float)ge;
        }
    }
    __syncthreads();

    // ---------------- Stage 3: logits = h2 @ w3 + b3, / max(T, 0.1)  (f64) ----------------
    const int q = tid & 7;   // col group: cols q*8 .. q*8+7
    const int r = tid >> 3;  // row 0..31
    double acc3[8];
    #pragma unroll
    for (int j = 0; j < 8; ++j) acc3[j] = 0.0;
    {
        const float* w3p = w3 + q * 8;
        for (int k = 0; k < H2D; ++k) {
            double hv = (double)sH2[r][k];
            float4 wa = *(const float4*)(w3p + (size_t)k * NE);
            float4 wb = *(const float4*)(w3p + (size_t)k * NE + 4);
            acc3[0] = fma(hv, (double)wa.x, acc3[0]);
            acc3[1] = fma(hv, (double)wa.y, acc3[1]);
            acc3[2] = fma(hv, (double)wa.z, acc3[2]);
            acc3[3] = fma(hv, (double)wa.w, acc3[3]);
            acc3[4] = fma(hv, (double)wb.x, acc3[4]);
            acc3[5] = fma(hv, (double)wb.y, acc3[5]);
            acc3[6] = fma(hv, (double)wb.z, acc3[6]);
            acc3[7] = fma(hv, (double)wb.w, acc3[7]);
        }
    }
    double tinv = 1.0 / fmax((double)temperature[0], 0.1);
    double lg[8];
    #pragma unroll
    for (int j = 0; j < 8; ++j) lg[j] = (acc3[j] + (double)b3[q * 8 + j]) * tinv;

    {
        float4 o0 = make_float4((float)lg[0], (float)lg[1], (float)lg[2], (float)lg[3]);
        float4 o1 = make_float4((float)lg[4], (float)lg[5], (float)lg[6], (float)lg[7]);
        *(float4*)(out_logits + (size_t)(r0 + r) * NE + q * 8)     = o0;
        *(float4*)(out_logits + (size_t)(r0 + r) * NE + q * 8 + 4) = o1;
    }

    // ---------------- top-2 in f64 (stable, lower index wins ties) ----------------
    double v1 = -INFINITY, v2 = -INFINITY;
    int i1 = 0, i2 = 0;
    #pragma unroll
    for (int j = 0; j < 8; ++j) {
        int c = q * 8 + j;
        double v = lg[j];
        if (v > v1)      { v2 = v1; i2 = i1; v1 = v; i1 = c; }
        else if (v > v2) { v2 = v;  i2 = c; }
    }
    #pragma unroll
    for (int m = 1; m < 8; m <<= 1) {
        double ov1 = __shfl_xor(v1, m, 64);
        int    oi1 = __shfl_xor(i1, m, 64);
        double ov2 = __shfl_xor(v2, m, 64);
        int    oi2 = __shfl_xor(i2, m, 64);
        bool aw = (v1 > ov1) || (v1 == ov1 && i1 < oi1);
        double wv = aw ? v1  : ov1;  int wi = aw ? i1  : oi1;
        double lv = aw ? ov1 : v1;   int li = aw ? oi1 : i1;
        double sv = aw ? v2  : ov2;  int si = aw ? i2  : oi2;
        bool sw = (sv > lv) || (sv == lv && si < li);
        v1 = wv; i1 = wi;
        v2 = sw ? sv : lv;
        i2 = sw ? si : li;
    }

    // pair softmax + renorm by (sum + 1e-8), f64
    double e2  = exp(v2 - v1);
    double den = 1.0 + e2;
    double tg1 = 1.0 / den;
    double tg2 = e2 / den;
    double ssum = tg1 + tg2 + 1e-8;
    float gv1 = (float)(tg1 / ssum);
    float gv2 = (float)(tg2 / ssum);

    if (q == 0) {
        out_idx[(size_t)(r0 + r) * 2 + 0] = (float)i1;  // indices stored as float values
        out_idx[(size_t)(r0 + r) * 2 + 1] = (float)i2;
        sTop[r][0] = (float)i1;
        sTop[r][1] = (float)i2;
        sTop[r][2] = gv1;
        sTop[r][3] = gv2;
    }
    __syncthreads();

    {
        int   ti1 = (int)sTop[r][0];
        int   ti2 = (int)sTop[r][1];
        float sg1 = sTop[r][2];
        float sg2 = sTop[r][3];
        float gv[8];
        #pragma unroll
        for (int j = 0; j < 8; ++j) {
            int c = q * 8 + j;
            gv[j] = (c == ti1) ? sg1 : ((c == ti2) ? sg2 : 0.0f);
        }
        float4 g0  = make_float4(gv[0], gv[1], gv[2], gv[3]);
        float4 g1o = make_float4(gv[4], gv[5], gv[6], gv[7]);
        *(float4*)(out_gates + (size_t)(r0 + r) * NE + q * 8)     = g0;
        *(float4*)(out_gates + (size_t)(r0 + r) * NE + q * 8 + 4) = g1o;
    }
}

extern "C" void kernel_launch(void* const* d_in, const int* in_sizes, int n_in,
                              void* d_out, int out_size, void* d_ws, size_t ws_size,
                              hipStream_t stream)
{
    const float* x    = (const float*)d_in[0];
    const float* w1   = (const float*)d_in[1];
    const float* b1   = (const float*)d_in[2];
    const float* g1   = (const float*)d_in[3];
    const float* be1  = (const float*)d_in[4];
    const float* w2   = (const float*)d_in[5];
    const float* b2   = (const float*)d_in[6];
    const float* g2   = (const float*)d_in[7];
    const float* be2  = (const float*)d_in[8];
    const float* w3   = (const float*)d_in[9];
    const float* b3   = (const float*)d_in[10];
    const float* temp = (const float*)d_in[11];

    float* gates  = (float*)d_out;
    float* idxf   = gates + (size_t)NROWS * NE;
    float* logits = idxf + (size_t)NROWS * 2;

    hipLaunchKernelGGL(fused_gate_kernel, dim3(NROWS / BM), dim3(NTHREADS), 0, stream,
                       x, w1, b1, g1, be1, w2, b2, g2, be2, w3, b3, temp,
                       gates, idxf, logits);
}